// Round 6
// baseline (476.734 us; speedup 1.0000x reference)
//
#include <hip/hip_runtime.h>
#include <hip/hip_bf16.h>

// Problem constants
#define BB 8
#define SS 4096
#define DD 2048
#define HH 16
#define HDIM 128
#define LL 16
#define JJ 256           // HH*LL, j = h*16 + l
#define ROWS (BB*SS)     // 32768
#define LN_EPS 1e-5f

typedef __attribute__((ext_vector_type(8))) short short8;
typedef __attribute__((ext_vector_type(4))) float f32x4;

typedef __attribute__((address_space(1))) const unsigned int gu32;
typedef __attribute__((address_space(3))) unsigned int lu32;
__device__ __forceinline__ void async16(const void* g, void* l) {
  __builtin_amdgcn_global_load_lds((gu32*)g, (lu32*)l, 16, 0, 0);
}

__device__ __forceinline__ unsigned short f2bf(float f) {
  unsigned int u = __builtin_bit_cast(unsigned int, f);
  u += 0x7fffu + ((u >> 16) & 1u);        // round-to-nearest-even
  return (unsigned short)(u >> 16);
}
__device__ __forceinline__ float bf2f(unsigned short u) {
  unsigned int v = ((unsigned int)u) << 16;
  return __builtin_bit_cast(float, v);
}

// ---------------------------------------------------------------- q partials: qpart[eb][l][c]
__global__ __launch_bounds__(256) void k_q_part(const float* latents, const float* w_lq, float* qpart) {
  int c  = blockIdx.x * 256 + threadIdx.x;  // 0..2047
  int e0 = blockIdx.y * 64;                 // 32 chunks
  float acc[16];
#pragma unroll
  for (int l = 0; l < 16; ++l) acc[l] = 0.f;
  for (int e = e0; e < e0 + 64; ++e) {
    float w = w_lq[(size_t)e * 2048 + c];
#pragma unroll
    for (int l = 0; l < 16; ++l) acc[l] += latents[l * 2048 + e] * w;
  }
#pragma unroll
  for (int l = 0; l < 16; ++l) qpart[((size_t)blockIdx.y * 16 + l) * 2048 + c] = acc[l];
}

// ---------------------------------------------------------------- 32-partial reduce: out[r][c] = bias[c] + sum_p part[p][r][c]
__global__ __launch_bounds__(256) void k_reduce(const float* part, const float* bias, float* out, int R) {
  int c = blockIdx.x * 256 + threadIdx.x;   // grid.x = 8
  int r = blockIdx.y;                       // grid.y = R
  float s = bias[c];
  for (int p = 0; p < 32; ++p) s += part[((size_t)p * R + r) * 2048 + c];
  out[r * 2048 + c] = s;
}

// ---------------------------------------------------------------- fused LN: h[row][e] = bf16(LN(x[row]))
__global__ __launch_bounds__(256) void k_lnT(const float* x, const float* ln_g, const float* ln_b,
                                             short* h) {
  int row = blockIdx.x;                     // 0..32767
  int t = threadIdx.x;
  const float4* xr = (const float4*)(x + (size_t)row * 2048);
  float4 v0 = xr[t * 2];
  float4 v1 = xr[t * 2 + 1];
  float s  = v0.x + v0.y + v0.z + v0.w + v1.x + v1.y + v1.z + v1.w;
  float s2 = v0.x*v0.x + v0.y*v0.y + v0.z*v0.z + v0.w*v0.w
           + v1.x*v1.x + v1.y*v1.y + v1.z*v1.z + v1.w*v1.w;
#pragma unroll
  for (int o = 32; o; o >>= 1) { s += __shfl_down(s, o); s2 += __shfl_down(s2, o); }
  __shared__ float red[8];
  int wid = t >> 6;
  if ((t & 63) == 0) { red[wid] = s; red[4 + wid] = s2; }
  __syncthreads();
  float ts  = red[0] + red[1] + red[2] + red[3];
  float ts2 = red[4] + red[5] + red[6] + red[7];
  float mu   = ts * (1.0f / 2048.0f);
  float var  = ts2 * (1.0f / 2048.0f) - mu * mu;
  float rstd = rsqrtf(var + LN_EPS);
  const float4* gp = (const float4*)ln_g;
  const float4* bp = (const float4*)ln_b;
  float4 g0 = gp[t * 2], g1 = gp[t * 2 + 1];
  float4 b0 = bp[t * 2], b1 = bp[t * 2 + 1];
  short8 o;
  o[0] = (short)f2bf((v0.x - mu) * rstd * g0.x + b0.x);
  o[1] = (short)f2bf((v0.y - mu) * rstd * g0.y + b0.y);
  o[2] = (short)f2bf((v0.z - mu) * rstd * g0.z + b0.z);
  o[3] = (short)f2bf((v0.w - mu) * rstd * g0.w + b0.w);
  o[4] = (short)f2bf((v1.x - mu) * rstd * g1.x + b1.x);
  o[5] = (short)f2bf((v1.y - mu) * rstd * g1.y + b1.y);
  o[6] = (short)f2bf((v1.z - mu) * rstd * g1.z + b1.z);
  o[7] = (short)f2bf((v1.w - mu) * rstd * g1.w + b1.w);
  ((short8*)(h + (size_t)row * 2048))[t] = o;
}

// ---------------------------------------------------------------- Wq_t[j][e]
__global__ __launch_bounds__(256) void k_wq(const float* w_k, const float* q, short* wq_t) {
  int e = blockIdx.x;                       // 0..2047
  __shared__ float wrow[2048];
  for (int i = threadIdx.x; i < 512; i += 256)
    ((float4*)wrow)[i] = ((const float4*)(w_k + (size_t)e * 2048))[i];
  __syncthreads();
  int j = threadIdx.x;
  int h = j >> 4, l = j & 15;
  const float* qrow = q + l * 2048 + h * 128;
  const float* wr = wrow + h * 128;
  float acc = 0.f;
#pragma unroll 8
  for (int d = 0; d < 128; ++d) acc += wr[d] * qrow[d];
  wq_t[(size_t)j * 2048 + e] = (short)f2bf(acc * 0.08838834764831845f);
}

// ---------------------------------------------------------------- scores[b][j][s] = Wq_t @ h^T
// Tile [64 j][256 s] per block; A (wq_t) 8KB/step, B (h) 32KB/step, dbuf 80KB LDS.
// Counted vmcnt(10) + two raw barriers per K-step: prefetch stays in flight.
__global__ __launch_bounds__(256, 2) void k_scores(const short* h, const short* wq_t, float* scores) {
  int s0 = blockIdx.x * 256;                // 16 s-tiles
  int j0 = blockIdx.y * 64;                 // 4 j-tiles
  int b  = blockIdx.z;
  __shared__ short lds[2 * 4096 + 2 * 16384];   // A dbuf 2x[64][64], B dbuf 2x[256][64]
  int t = threadIdx.x, lane = t & 63, w = t >> 6;
  f32x4 zero = {0.f, 0.f, 0.f, 0.f};
  f32x4 acc[4][4];
#pragma unroll
  for (int m = 0; m < 4; ++m)
#pragma unroll
    for (int n = 0; n < 4; ++n) acc[m][n] = zero;

  // staging: chunk = i*256 + t -> row = i*32 + (t>>3), slot kc = t&7; src chunk = kc ^ (row&7)
  int rsel = t >> 3;
  int kcs  = (t & 7) ^ ((t >> 3) & 7);
  const short* hbase  = h + ((size_t)(b * 4096 + s0)) * 2048;
  const short* wqbase = wq_t + (size_t)j0 * 2048;
  // ds_read swizzled k-offset (shorts): desired chunk (kk*4+hi) ^ (row&7); row&7 == lane&7
  int koff0 = (((lane >> 4)) ^ (lane & 7)) * 8;
  int koff1 = ((4 + (lane >> 4)) ^ (lane & 7)) * 8;

  int cur = 0;
  // prologue: stage K-step 0 into buf 0  (10 loads: 8 B + 2 A)
  {
    short* lA = lds;
    short* lB = lds + 8192;
#pragma unroll
    for (int i = 0; i < 8; ++i)
      async16(hbase + (size_t)(i * 32 + rsel) * 2048 + kcs * 8,
              lB + (i * 256 + w * 64) * 8);
#pragma unroll
    for (int i = 0; i < 2; ++i)
      async16(wqbase + (size_t)(i * 32 + rsel) * 2048 + kcs * 8,
              lA + (i * 256 + w * 64) * 8);
  }

  for (int it = 0; it < 32; ++it) {
    if (it < 31) {                       // stage next K-step into other buffer
      int k0 = (it + 1) * 64;
      short* lA1 = lds + (cur ^ 1) * 4096;
      short* lB1 = lds + 8192 + (cur ^ 1) * 16384;
#pragma unroll
      for (int i = 0; i < 8; ++i)
        async16(hbase + (size_t)(i * 32 + rsel) * 2048 + k0 + kcs * 8,
                lB1 + (i * 256 + w * 64) * 8);
#pragma unroll
      for (int i = 0; i < 2; ++i)
        async16(wqbase + (size_t)(i * 32 + rsel) * 2048 + k0 + kcs * 8,
                lA1 + (i * 256 + w * 64) * 8);
      asm volatile("s_waitcnt vmcnt(10)" ::: "memory");   // current buf landed; 10 in flight
    } else {
      asm volatile("s_waitcnt vmcnt(0)" ::: "memory");    // last buf: full drain
    }
    __builtin_amdgcn_s_barrier();        // all waves' staging of cur visible
    __builtin_amdgcn_sched_barrier(0);
    const short* lA = lds + cur * 4096;
    const short* lB = lds + 8192 + cur * 16384;
#pragma unroll
    for (int kk = 0; kk < 2; ++kk) {
      int ko = kk ? koff1 : koff0;
      short8 afr[4];
#pragma unroll
      for (int m = 0; m < 4; ++m)
        afr[m] = *(const short8*)(lA + (m * 16 + (lane & 15)) * 64 + ko);
#pragma unroll
      for (int n = 0; n < 4; ++n) {
        short8 bfr = *(const short8*)(lB + (w * 64 + n * 16 + (lane & 15)) * 64 + ko);
#pragma unroll
        for (int m = 0; m < 4; ++m)
          acc[m][n] = __builtin_amdgcn_mfma_f32_16x16x32_bf16(afr[m], bfr, acc[m][n], 0, 0, 0);
      }
    }
    __builtin_amdgcn_s_barrier();        // reads of cur done before next overwrite
    cur ^= 1;
  }

  int r4 = (lane >> 4) * 4, cc = lane & 15;
#pragma unroll
  for (int m = 0; m < 4; ++m) {
    int j = j0 + m * 16 + r4;
#pragma unroll
    for (int n = 0; n < 4; ++n) {
      int s = s0 + w * 64 + n * 16 + cc;
      float* dst = scores + ((size_t)b * 256 + j) * 4096 + s;
#pragma unroll
      for (int i = 0; i < 4; ++i) dst[(size_t)i * 4096] = acc[m][n][i];
    }
  }
}

// ---------------------------------------------------------------- softmax pass A: per-row max + 1/(16*sum)
__global__ __launch_bounds__(256) void k_smax_a(const float* scores, float* msum) {
  int j = blockIdx.x, b = blockIdx.y;
  const float* row = scores + ((size_t)b * 256 + j) * 4096;
  float v[16];
  float mx = -1e30f;
#pragma unroll
  for (int i = 0; i < 16; ++i) { v[i] = row[threadIdx.x + 256 * i]; mx = fmaxf(mx, v[i]); }
#pragma unroll
  for (int o = 32; o; o >>= 1) mx = fmaxf(mx, __shfl_xor(mx, o));
  __shared__ float redm[4], reds[4];
  if ((threadIdx.x & 63) == 0) redm[threadIdx.x >> 6] = mx;
  __syncthreads();
  mx = fmaxf(fmaxf(redm[0], redm[1]), fmaxf(redm[2], redm[3]));
  float sum = 0.f;
#pragma unroll
  for (int i = 0; i < 16; ++i) sum += __expf(v[i] - mx);
#pragma unroll
  for (int o = 32; o; o >>= 1) sum += __shfl_xor(sum, o);
  if ((threadIdx.x & 63) == 0) reds[threadIdx.x >> 6] = sum;
  __syncthreads();
  if (threadIdx.x == 0) {
    sum = reds[0] + reds[1] + reds[2] + reds[3];
    msum[(b * 256 + j) * 2]     = mx;
    msum[(b * 256 + j) * 2 + 1] = 1.0f / (16.0f * sum);
  }
}

// ---------------------------------------------------------------- softmax pass B: pbar[b][h][s] = sum_l exp(sc-m)*inv16
__global__ __launch_bounds__(256) void k_smax_b(const float* scores, const float* msum, float* pbar) {
  int b = blockIdx.y, sc = blockIdx.x;      // 64 s-chunks of 64
  int t = threadIdx.x, lane = t & 63, jq = t >> 6;
  int s = sc * 64 + lane;
  const float* srow = scores + ((size_t)(b * 256 + jq * 64)) * 4096 + s;
  const float* ms = msum + (b * 256 + jq * 64) * 2;
  float acc[4] = {0.f, 0.f, 0.f, 0.f};
  for (int jj = 0; jj < 64; ++jj) {
    float m  = ms[jj * 2];
    float iv = ms[jj * 2 + 1];
    float v = __expf(srow[(size_t)jj * 4096] - m) * iv;
    acc[jj >> 4] += v;
  }
#pragma unroll
  for (int r = 0; r < 4; ++r)
    pbar[((size_t)b * 16 + jq * 4 + r) * 4096 + s] = acc[r];
}

// ---------------------------------------------------------------- Tbar partials: Tpart[sp][b][h][e], sp = 32 chunks of 128 s
__global__ __launch_bounds__(256) void k_tbar2(const short* h, const float* pbar, float* Tpart) {
  int ec = blockIdx.x;                      // 0..1 (e-chunks of 1024)
  int sp = blockIdx.y;                      // 0..31 (s-chunks of 128)
  int b  = blockIdx.z;
  int t  = threadIdx.x;
  int e0 = ec * 1024 + t * 4;
  __shared__ float lp[16 * 128];            // pbar chunk [h][s]
  {
    int hh = t >> 4, so = (t & 15) * 8;
    const float4* src = (const float4*)(pbar + ((size_t)b * 16 + hh) * 4096 + sp * 128 + so);
    float4* dst = (float4*)(lp + hh * 128 + so);
    dst[0] = src[0]; dst[1] = src[1];
  }
  __syncthreads();
  f32x4 acc[16];
#pragma unroll
  for (int hh = 0; hh < 16; ++hh) acc[hh] = (f32x4){0.f, 0.f, 0.f, 0.f};

  const short* hbase = h + ((size_t)(b * 4096 + sp * 128)) * 2048 + e0;
  for (int si = 0; si < 128; si += 4) {
    float hv[4][4];
#pragma unroll
    for (int r = 0; r < 4; ++r) {
      short4 hh4 = *(const short4*)(hbase + (size_t)(si + r) * 2048);
      hv[r][0] = bf2f((unsigned short)hh4.x);
      hv[r][1] = bf2f((unsigned short)hh4.y);
      hv[r][2] = bf2f((unsigned short)hh4.z);
      hv[r][3] = bf2f((unsigned short)hh4.w);
    }
#pragma unroll
    for (int hh = 0; hh < 16; ++hh) {
      float4 ph = *(const float4*)(lp + hh * 128 + si);
#pragma unroll
      for (int c = 0; c < 4; ++c)
        acc[hh][c] += ph.x * hv[0][c] + ph.y * hv[1][c] + ph.z * hv[2][c] + ph.w * hv[3][c];
    }
  }
#pragma unroll
  for (int hh = 0; hh < 16; ++hh)
    *(f32x4*)(Tpart + ((size_t)((sp * 8 + b) * 16 + hh)) * 2048 + e0) = acc[hh];
}

// ---------------------------------------------------------------- Tbar[bh][e] = sum_sp Tpart[sp][bh][e]
__global__ __launch_bounds__(256) void k_tred(const float* Tpart, float* Tbar) {
  int bh = blockIdx.x;                      // 0..127 (= b*16+h)
  for (int e = threadIdx.x; e < 2048; e += 256) {
    float s = 0.f;
#pragma unroll
    for (int p = 0; p < 32; ++p) s += Tpart[((size_t)p * 128 + bh) * 2048 + e];
    Tbar[(size_t)bh * 2048 + e] = s;
  }
}

// ---------------------------------------------------------------- cbar partials over e: part[eb][b][c]
__global__ __launch_bounds__(256) void k_cbar_part(const float* Tbar, const float* w_v, float* part) {
  int c  = blockIdx.x * 256 + threadIdx.x;
  int e0 = blockIdx.y * 64;
  int h  = c >> 7;
  float acc[8];
#pragma unroll
  for (int b = 0; b < 8; ++b) acc[b] = 0.f;
  for (int e = e0; e < e0 + 64; ++e) {
    float wv = w_v[(size_t)e * 2048 + c];
#pragma unroll
    for (int b = 0; b < 8; ++b) acc[b] += Tbar[((size_t)b * 16 + h) * 2048 + e] * wv;
  }
#pragma unroll
  for (int b = 0; b < 8; ++b) part[((size_t)blockIdx.y * 8 + b) * 2048 + c] = acc[b];
}

// ---------------------------------------------------------------- vecmat partials over e: part[eb][b][c]
__global__ __launch_bounds__(256) void k_vecmat_part(const float* vin, const float* W, float* part) {
  int c  = blockIdx.x * 256 + threadIdx.x;
  int e0 = blockIdx.y * 64;
  float acc[8];
#pragma unroll
  for (int b = 0; b < 8; ++b) acc[b] = 0.f;
  for (int e = e0; e < e0 + 64; ++e) {
    float wv = W[(size_t)e * 2048 + c];
#pragma unroll
    for (int b = 0; b < 8; ++b) acc[b] += vin[b * 2048 + e] * wv;
  }
#pragma unroll
  for (int b = 0; b < 8; ++b) part[((size_t)blockIdx.y * 8 + b) * 2048 + c] = acc[b];
}

// ---------------------------------------------------------------- out = x + broadcast(outv)   (fp32)
__global__ __launch_bounds__(256) void k_resid(const float* x, const float* outv, float* out) {
  size_t i4 = (size_t)blockIdx.x * 256 + threadIdx.x;
  size_t total4 = (size_t)ROWS * 512;
  size_t stride = (size_t)gridDim.x * 256;
  for (; i4 < total4; i4 += stride) {
    int b  = (int)(i4 >> 21);               // 4096*512 float4 per batch
    int c4 = (int)(i4 & 511);
    float4 xv = ((const float4*)x)[i4];
    float4 ov = ((const float4*)outv)[b * 512 + c4];
    float4 o;
    o.x = xv.x + ov.x; o.y = xv.y + ov.y;
    o.z = xv.z + ov.z; o.w = xv.w + ov.w;
    ((float4*)out)[i4] = o;
  }
}

// ================================================================ launch
extern "C" void kernel_launch(void* const* d_in, const int* in_sizes, int n_in,
                              void* d_out, int out_size, void* d_ws, size_t ws_size,
                              hipStream_t stream) {
  const float* x       = (const float*)d_in[0];
  const float* ln_g    = (const float*)d_in[1];
  const float* ln_b    = (const float*)d_in[2];
  const float* latents = (const float*)d_in[3];
  const float* w_lq    = (const float*)d_in[4];
  const float* b_lq    = (const float*)d_in[5];
  const float* w_k     = (const float*)d_in[6];
  // const float* b_k  = (const float*)d_in[7];   // softmax-invariant, unused
  const float* w_v     = (const float*)d_in[8];
  const float* b_v     = (const float*)d_in[9];
  const float* w_lv    = (const float*)d_in[10];
  const float* b_lv    = (const float*)d_in[11];
  const float* w_out   = (const float*)d_in[12];
  const float* b_out   = (const float*)d_in[13];

  // d_out is fp32 [8,4096,2048] = 268 MB; first ~210 MB doubles as scratch,
  // all dead before k_resid overwrites the full buffer. outv lives in d_ws.
  char* base = (char*)d_out;
  float* scores = (float*)(base);                        //  33,554,432 B
  short* h      = (short*)(base + 33554432);             // 134,217,728 B (bf16 LN(x))
  float* Tpart  = (float*)(base + 167772160);            //  33,554,432 B
  float* pbar   = (float*)(base + 201326592);            //   2,097,152 B
  float* msum   = (float*)(base + 203423744);            //      16,384 B
  float* q      = (float*)(base + 203440128);            //     131,072 B
  short* wq_t   = (short*)(base + 203571200);            //   1,048,576 B
  float* Tbar   = (float*)(base + 204619776);            //     524,288 B
  float* cbar   = (float*)(base + 205144064);            //      65,536 B
  float* pooled = (float*)(base + 205209600);            //      65,536 B
  float* part   = (float*)(base + 205275136);            //   4,194,304 B
  float* outv   = (float*)d_ws;                          //      65,536 B
  float* out    = (float*)d_out;

  k_q_part     <<<dim3(8, 32), 256, 0, stream>>>(latents, w_lq, part);
  k_reduce     <<<dim3(8, 16), 256, 0, stream>>>(part, b_lq, q, 16);
  k_lnT        <<<32768, 256, 0, stream>>>(x, ln_g, ln_b, h);
  k_wq         <<<2048, 256, 0, stream>>>(w_k, q, wq_t);
  k_scores     <<<dim3(16, 4, 8), 256, 0, stream>>>(h, wq_t, scores);
  k_smax_a     <<<dim3(256, 8), 256, 0, stream>>>(scores, msum);
  k_smax_b     <<<dim3(64, 8), 256, 0, stream>>>(scores, msum, pbar);
  k_tbar2      <<<dim3(2, 32, 8), 256, 0, stream>>>(h, pbar, Tpart);
  k_tred       <<<128, 256, 0, stream>>>(Tpart, Tbar);
  k_cbar_part  <<<dim3(8, 32), 256, 0, stream>>>(Tbar, w_v, part);
  k_reduce     <<<dim3(8, 8), 256, 0, stream>>>(part, b_v, cbar, 8);
  k_vecmat_part<<<dim3(8, 32), 256, 0, stream>>>(cbar, w_lv, part);
  k_reduce     <<<dim3(8, 8), 256, 0, stream>>>(part, b_lv, pooled, 8);
  k_vecmat_part<<<dim3(8, 32), 256, 0, stream>>>(pooled, w_out, part);
  k_reduce     <<<dim3(8, 8), 256, 0, stream>>>(part, b_out, outv, 8);
  k_resid      <<<2048, 256, 0, stream>>>(x, outv, out);
}

// Round 7
// 451.294 us; speedup vs baseline: 1.0564x; 1.0564x over previous
//
#include <hip/hip_runtime.h>
#include <hip/hip_bf16.h>

// Problem constants
#define BB 8
#define SS 4096
#define DD 2048
#define HH 16
#define HDIM 128
#define LL 16
#define JJ 256           // HH*LL, j = h*16 + l
#define ROWS (BB*SS)     // 32768
#define LN_EPS 1e-5f

typedef __attribute__((ext_vector_type(8))) short short8;
typedef __attribute__((ext_vector_type(4))) float f32x4;

typedef __attribute__((address_space(1))) const unsigned int gu32;
typedef __attribute__((address_space(3))) unsigned int lu32;
__device__ __forceinline__ void async16(const void* g, void* l) {
  __builtin_amdgcn_global_load_lds((gu32*)g, (lu32*)l, 16, 0, 0);
}

__device__ __forceinline__ unsigned short f2bf(float f) {
  unsigned int u = __builtin_bit_cast(unsigned int, f);
  u += 0x7fffu + ((u >> 16) & 1u);        // round-to-nearest-even
  return (unsigned short)(u >> 16);
}
__device__ __forceinline__ float bf2f(unsigned short u) {
  unsigned int v = ((unsigned int)u) << 16;
  return __builtin_bit_cast(float, v);
}

// ---------------------------------------------------------------- q partials: qpart[eb][l][c]
__global__ __launch_bounds__(256) void k_q_part(const float* latents, const float* w_lq, float* qpart) {
  int c  = blockIdx.x * 256 + threadIdx.x;  // 0..2047
  int e0 = blockIdx.y * 64;                 // 32 chunks
  float acc[16];
#pragma unroll
  for (int l = 0; l < 16; ++l) acc[l] = 0.f;
  for (int e = e0; e < e0 + 64; ++e) {
    float w = w_lq[(size_t)e * 2048 + c];
#pragma unroll
    for (int l = 0; l < 16; ++l) acc[l] += latents[l * 2048 + e] * w;
  }
#pragma unroll
  for (int l = 0; l < 16; ++l) qpart[((size_t)blockIdx.y * 16 + l) * 2048 + c] = acc[l];
}

// ---------------------------------------------------------------- 32-partial reduce: out[r][c] = bias[c] + sum_p part[p][r][c]
__global__ __launch_bounds__(256) void k_reduce(const float* part, const float* bias, float* out, int R) {
  int c = blockIdx.x * 256 + threadIdx.x;   // grid.x = 8
  int r = blockIdx.y;                       // grid.y = R
  float s = bias[c];
  for (int p = 0; p < 32; ++p) s += part[((size_t)p * R + r) * 2048 + c];
  out[r * 2048 + c] = s;
}

// ---------------------------------------------------------------- fused LN: h[row][e] = bf16(LN(x[row]))
__global__ __launch_bounds__(256) void k_lnT(const float* x, const float* ln_g, const float* ln_b,
                                             short* h) {
  int row = blockIdx.x;                     // 0..32767
  int t = threadIdx.x;
  const float4* xr = (const float4*)(x + (size_t)row * 2048);
  float4 v0 = xr[t * 2];
  float4 v1 = xr[t * 2 + 1];
  float s  = v0.x + v0.y + v0.z + v0.w + v1.x + v1.y + v1.z + v1.w;
  float s2 = v0.x*v0.x + v0.y*v0.y + v0.z*v0.z + v0.w*v0.w
           + v1.x*v1.x + v1.y*v1.y + v1.z*v1.z + v1.w*v1.w;
#pragma unroll
  for (int o = 32; o; o >>= 1) { s += __shfl_down(s, o); s2 += __shfl_down(s2, o); }
  __shared__ float red[8];
  int wid = t >> 6;
  if ((t & 63) == 0) { red[wid] = s; red[4 + wid] = s2; }
  __syncthreads();
  float ts  = red[0] + red[1] + red[2] + red[3];
  float ts2 = red[4] + red[5] + red[6] + red[7];
  float mu   = ts * (1.0f / 2048.0f);
  float var  = ts2 * (1.0f / 2048.0f) - mu * mu;
  float rstd = rsqrtf(var + LN_EPS);
  const float4* gp = (const float4*)ln_g;
  const float4* bp = (const float4*)ln_b;
  float4 g0 = gp[t * 2], g1 = gp[t * 2 + 1];
  float4 b0 = bp[t * 2], b1 = bp[t * 2 + 1];
  short8 o;
  o[0] = (short)f2bf((v0.x - mu) * rstd * g0.x + b0.x);
  o[1] = (short)f2bf((v0.y - mu) * rstd * g0.y + b0.y);
  o[2] = (short)f2bf((v0.z - mu) * rstd * g0.z + b0.z);
  o[3] = (short)f2bf((v0.w - mu) * rstd * g0.w + b0.w);
  o[4] = (short)f2bf((v1.x - mu) * rstd * g1.x + b1.x);
  o[5] = (short)f2bf((v1.y - mu) * rstd * g1.y + b1.y);
  o[6] = (short)f2bf((v1.z - mu) * rstd * g1.z + b1.z);
  o[7] = (short)f2bf((v1.w - mu) * rstd * g1.w + b1.w);
  ((short8*)(h + (size_t)row * 2048))[t] = o;
}

// ---------------------------------------------------------------- Wq_t[j][e]
__global__ __launch_bounds__(256) void k_wq(const float* w_k, const float* q, short* wq_t) {
  int e = blockIdx.x;                       // 0..2047
  __shared__ float wrow[2048];
  for (int i = threadIdx.x; i < 512; i += 256)
    ((float4*)wrow)[i] = ((const float4*)(w_k + (size_t)e * 2048))[i];
  __syncthreads();
  int j = threadIdx.x;
  int h = j >> 4, l = j & 15;
  const float* qrow = q + l * 2048 + h * 128;
  const float* wr = wrow + h * 128;
  float acc = 0.f;
#pragma unroll 8
  for (int d = 0; d < 128; ++d) acc += wr[d] * qrow[d];
  wq_t[(size_t)j * 2048 + e] = (short)f2bf(acc * 0.08838834764831845f);
}

// ---------------------------------------------------------------- scores[b][j][s] (bf16) = Wq_t @ h^T
// + fused per-(row, s-tile) softmax partials (max, sum-of-exp of bf16-rounded vals)
__global__ __launch_bounds__(256, 2) void k_scores(const short* h, const short* wq_t,
                                                   short* scores, float* part_ms) {
  int s0 = blockIdx.x * 256;                // 16 s-tiles
  int j0 = blockIdx.y * 64;                 // 4 j-tiles
  int b  = blockIdx.z;
  __shared__ short lds[2 * 4096 + 2 * 16384];   // A dbuf 2x[64][64], B dbuf 2x[256][64]
  int t = threadIdx.x, lane = t & 63, w = t >> 6;
  f32x4 zero = {0.f, 0.f, 0.f, 0.f};
  f32x4 acc[4][4];
#pragma unroll
  for (int m = 0; m < 4; ++m)
#pragma unroll
    for (int n = 0; n < 4; ++n) acc[m][n] = zero;

  int rsel = t >> 3;
  int kcs  = (t & 7) ^ ((t >> 3) & 7);
  const short* hbase  = h + ((size_t)(b * 4096 + s0)) * 2048;
  const short* wqbase = wq_t + (size_t)j0 * 2048;
  int koff0 = (((lane >> 4)) ^ (lane & 7)) * 8;
  int koff1 = ((4 + (lane >> 4)) ^ (lane & 7)) * 8;

  int cur = 0;
  { // prologue: stage K-step 0 into buf 0
    short* lA = lds;
    short* lB = lds + 8192;
#pragma unroll
    for (int i = 0; i < 8; ++i)
      async16(hbase + (size_t)(i * 32 + rsel) * 2048 + kcs * 8,
              lB + (i * 256 + w * 64) * 8);
#pragma unroll
    for (int i = 0; i < 2; ++i)
      async16(wqbase + (size_t)(i * 32 + rsel) * 2048 + kcs * 8,
              lA + (i * 256 + w * 64) * 8);
  }

  for (int it = 0; it < 32; ++it) {
    if (it < 31) {
      int k0 = (it + 1) * 64;
      short* lA1 = lds + (cur ^ 1) * 4096;
      short* lB1 = lds + 8192 + (cur ^ 1) * 16384;
#pragma unroll
      for (int i = 0; i < 8; ++i)
        async16(hbase + (size_t)(i * 32 + rsel) * 2048 + k0 + kcs * 8,
                lB1 + (i * 256 + w * 64) * 8);
#pragma unroll
      for (int i = 0; i < 2; ++i)
        async16(wqbase + (size_t)(i * 32 + rsel) * 2048 + k0 + kcs * 8,
                lA1 + (i * 256 + w * 64) * 8);
      asm volatile("s_waitcnt vmcnt(10)" ::: "memory");
    } else {
      asm volatile("s_waitcnt vmcnt(0)" ::: "memory");
    }
    __builtin_amdgcn_s_barrier();
    __builtin_amdgcn_sched_barrier(0);
    const short* lA = lds + cur * 4096;
    const short* lB = lds + 8192 + cur * 16384;
#pragma unroll
    for (int kk = 0; kk < 2; ++kk) {
      int ko = kk ? koff1 : koff0;
      short8 afr[4];
#pragma unroll
      for (int m = 0; m < 4; ++m)
        afr[m] = *(const short8*)(lA + (m * 16 + (lane & 15)) * 64 + ko);
#pragma unroll
      for (int n = 0; n < 4; ++n) {
        short8 bfr = *(const short8*)(lB + (w * 64 + n * 16 + (lane & 15)) * 64 + ko);
#pragma unroll
        for (int m = 0; m < 4; ++m)
          acc[m][n] = __builtin_amdgcn_mfma_f32_16x16x32_bf16(afr[m], bfr, acc[m][n], 0, 0, 0);
      }
    }
    __builtin_amdgcn_s_barrier();
    cur ^= 1;
  }

  // ---- epilogue: bf16 store + per-row (max, sum-exp) partials over this 256-s tile
  int hi = lane >> 4, cc = lane & 15;
  __syncthreads();                       // loop done for all waves; reuse lds as scratch
  float2* msred = (float2*)lds;          // [64 j_local][4 w]
#pragma unroll
  for (int m = 0; m < 4; ++m) {
#pragma unroll
    for (int i = 0; i < 4; ++i) {
      int j = j0 + m * 16 + hi * 4 + i;
      float v[4];
#pragma unroll
      for (int n = 0; n < 4; ++n) {
        unsigned short u = f2bf(acc[m][n][i]);
        scores[((size_t)(b * 256 + j)) * 4096 + s0 + w * 64 + n * 16 + cc] = (short)u;
        v[n] = bf2f(u);
      }
      float mx = fmaxf(fmaxf(v[0], v[1]), fmaxf(v[2], v[3]));
#pragma unroll
      for (int o = 1; o < 16; o <<= 1) mx = fmaxf(mx, __shfl_xor(mx, o));
      float sm = __expf(v[0] - mx) + __expf(v[1] - mx) + __expf(v[2] - mx) + __expf(v[3] - mx);
#pragma unroll
      for (int o = 1; o < 16; o <<= 1) sm += __shfl_xor(sm, o);
      if (cc == 0) msred[(m * 16 + hi * 4 + i) * 4 + w] = make_float2(mx, sm);
    }
  }
  __syncthreads();
  if (t < 64) {
    float2 p0 = msred[t * 4 + 0], p1 = msred[t * 4 + 1];
    float2 p2 = msred[t * 4 + 2], p3 = msred[t * 4 + 3];
    float M = fmaxf(fmaxf(p0.x, p1.x), fmaxf(p2.x, p3.x));
    float S = p0.y * __expf(p0.x - M) + p1.y * __expf(p1.x - M)
            + p2.y * __expf(p2.x - M) + p3.y * __expf(p3.x - M);
    ((float2*)part_ms)[((size_t)(b * 256 + j0 + t)) * 16 + blockIdx.x] = make_float2(M, S);
  }
}

// ---------------------------------------------------------------- combine 16 tile-partials per row
__global__ __launch_bounds__(256) void k_msum(const float* part_ms, float* msum) {
  int row = blockIdx.x * 256 + threadIdx.x;  // 0..2047
  const float2* p = (const float2*)(part_ms + (size_t)row * 32);
  float2 v[16];
  float M = -1e30f;
#pragma unroll
  for (int i = 0; i < 16; ++i) { v[i] = p[i]; M = fmaxf(M, v[i].x); }
  float S = 0.f;
#pragma unroll
  for (int i = 0; i < 16; ++i) S += v[i].y * __expf(v[i].x - M);
  msum[row * 2]     = M;
  msum[row * 2 + 1] = 1.0f / (16.0f * S);
}

// ---------------------------------------------------------------- fused pbar + h contraction:
// Tpart[sp*128 + b*16 + hh][e] = sum_{s in chunk} pbar[hh][s] * h[s][e]
__global__ __launch_bounds__(256) void k_pt(const short* scores, const float* msum,
                                            const short* h, float* Tpart) {
  int sp = blockIdx.x;                      // 0..31 (s-chunks of 128)
  int b  = blockIdx.y;
  int t  = threadIdx.x;
  __shared__ short sc[256 * 128];           // scores chunk [j][s], 64 KB
  __shared__ float lp[16 * 128];            // pbar [h][s], 8 KB
#pragma unroll
  for (int rr = 0; rr < 2; ++rr) {
    int j = rr * 128 + (t >> 1);
    const short8* src = (const short8*)(scores + ((size_t)(b * 256 + j)) * 4096 + sp * 128 + (t & 1) * 64);
    short8* dst = (short8*)(sc + j * 128 + (t & 1) * 64);
#pragma unroll
    for (int i = 0; i < 8; ++i) dst[i] = src[i];
  }
  __syncthreads();
  {
    int s = t & 127, hg = (t >> 7) * 8;
    for (int hh = hg; hh < hg + 8; ++hh) {
      const float* ms = msum + (b * 256 + hh * 16) * 2;
      float accp = 0.f;
#pragma unroll
      for (int l = 0; l < 16; ++l)
        accp += __expf(bf2f((unsigned short)sc[(hh * 16 + l) * 128 + s]) - ms[l * 2]) * ms[l * 2 + 1];
      lp[hh * 128 + s] = accp;
    }
  }
  __syncthreads();
  f32x4 a0[16], a1[16];
#pragma unroll
  for (int hh = 0; hh < 16; ++hh) { a0[hh] = (f32x4){0,0,0,0}; a1[hh] = (f32x4){0,0,0,0}; }
  const short* hb = h + ((size_t)(b * 4096 + sp * 128)) * 2048 + t * 8;
  for (int si = 0; si < 128; ++si) {
    short8 hv8 = *(const short8*)(hb + (size_t)si * 2048);
    float hv[8];
#pragma unroll
    for (int c = 0; c < 8; ++c) hv[c] = bf2f((unsigned short)hv8[c]);
#pragma unroll
    for (int hh = 0; hh < 16; ++hh) {
      float p = lp[hh * 128 + si];
#pragma unroll
      for (int c = 0; c < 4; ++c) { a0[hh][c] += p * hv[c]; a1[hh][c] += p * hv[4 + c]; }
    }
  }
#pragma unroll
  for (int hh = 0; hh < 16; ++hh) {
    float* dst = Tpart + ((size_t)(sp * 128 + b * 16 + hh)) * 2048 + t * 8;
    *(f32x4*)dst = a0[hh];
    *(f32x4*)(dst + 4) = a1[hh];
  }
}

// ---------------------------------------------------------------- Tbar[bh][e] = sum_sp Tpart[sp][bh][e]
__global__ __launch_bounds__(256) void k_tred(const float* Tpart, float* Tbar) {
  int bh = blockIdx.x;                      // 0..127
  int e  = blockIdx.y * 1024 + threadIdx.x;
#pragma unroll
  for (int k = 0; k < 4; ++k, e += 256) {
    float s = 0.f;
#pragma unroll
    for (int p = 0; p < 32; ++p) s += Tpart[((size_t)p * 128 + bh) * 2048 + e];
    Tbar[(size_t)bh * 2048 + e] = s;
  }
}

// ---------------------------------------------------------------- cbar partials over e: part[eb][b][c]
__global__ __launch_bounds__(256) void k_cbar_part(const float* Tbar, const float* w_v, float* part) {
  int c  = blockIdx.x * 256 + threadIdx.x;
  int e0 = blockIdx.y * 64;
  int h  = c >> 7;
  float acc[8];
#pragma unroll
  for (int b = 0; b < 8; ++b) acc[b] = 0.f;
  for (int e = e0; e < e0 + 64; ++e) {
    float wv = w_v[(size_t)e * 2048 + c];
#pragma unroll
    for (int b = 0; b < 8; ++b) acc[b] += Tbar[((size_t)b * 16 + h) * 2048 + e] * wv;
  }
#pragma unroll
  for (int b = 0; b < 8; ++b) part[((size_t)blockIdx.y * 8 + b) * 2048 + c] = acc[b];
}

// ---------------------------------------------------------------- vecmat partials over e: part[eb][b][c]
__global__ __launch_bounds__(256) void k_vecmat_part(const float* vin, const float* W, float* part) {
  int c  = blockIdx.x * 256 + threadIdx.x;
  int e0 = blockIdx.y * 64;
  float acc[8];
#pragma unroll
  for (int b = 0; b < 8; ++b) acc[b] = 0.f;
  for (int e = e0; e < e0 + 64; ++e) {
    float wv = W[(size_t)e * 2048 + c];
#pragma unroll
    for (int b = 0; b < 8; ++b) acc[b] += vin[b * 2048 + e] * wv;
  }
#pragma unroll
  for (int b = 0; b < 8; ++b) part[((size_t)blockIdx.y * 8 + b) * 2048 + c] = acc[b];
}

// ---------------------------------------------------------------- out = x + broadcast(outv)   (fp32)
__global__ __launch_bounds__(256) void k_resid(const float* x, const float* outv, float* out) {
  size_t i4 = (size_t)blockIdx.x * 256 + threadIdx.x;
  size_t total4 = (size_t)ROWS * 512;
  size_t stride = (size_t)gridDim.x * 256;
  for (; i4 < total4; i4 += stride) {
    int b  = (int)(i4 >> 21);               // 4096*512 float4 per batch
    int c4 = (int)(i4 & 511);
    float4 xv = ((const float4*)x)[i4];
    float4 ov = ((const float4*)outv)[b * 512 + c4];
    float4 o;
    o.x = xv.x + ov.x; o.y = xv.y + ov.y;
    o.z = xv.z + ov.z; o.w = xv.w + ov.w;
    ((float4*)out)[i4] = o;
  }
}

// ================================================================ launch
extern "C" void kernel_launch(void* const* d_in, const int* in_sizes, int n_in,
                              void* d_out, int out_size, void* d_ws, size_t ws_size,
                              hipStream_t stream) {
  const float* x       = (const float*)d_in[0];
  const float* ln_g    = (const float*)d_in[1];
  const float* ln_b    = (const float*)d_in[2];
  const float* latents = (const float*)d_in[3];
  const float* w_lq    = (const float*)d_in[4];
  const float* b_lq    = (const float*)d_in[5];
  const float* w_k     = (const float*)d_in[6];
  // const float* b_k  = (const float*)d_in[7];   // softmax-invariant, unused
  const float* w_v     = (const float*)d_in[8];
  const float* b_v     = (const float*)d_in[9];
  const float* w_lv    = (const float*)d_in[10];
  const float* b_lv    = (const float*)d_in[11];
  const float* w_out   = (const float*)d_in[12];
  const float* b_out   = (const float*)d_in[13];

  // d_out is fp32 [8,4096,2048] = 268 MB; first ~191 MB doubles as scratch,
  // all dead before k_resid overwrites the full buffer. outv lives in d_ws.
  char* base = (char*)d_out;
  short* scores  = (short*)(base);                       //  16,777,216 B (bf16)
  short* h       = (short*)(base + 16777216);            // 134,217,728 B (bf16 LN(x))
  float* Tpart   = (float*)(base + 150994944);           //  33,554,432 B
  float* part_ms = (float*)(base + 184549376);           //     262,144 B
  float* msum    = (float*)(base + 184811520);           //      16,384 B
  float* q       = (float*)(base + 184827904);           //     131,072 B
  short* wq_t    = (short*)(base + 184958976);           //   1,048,576 B
  float* Tbar    = (float*)(base + 186007552);           //     524,288 B
  float* cbar    = (float*)(base + 186531840);           //      65,536 B
  float* pooled  = (float*)(base + 186597376);           //      65,536 B
  float* part    = (float*)(base + 186662912);           //   4,194,304 B
  float* outv    = (float*)d_ws;                         //      65,536 B
  float* out     = (float*)d_out;

  k_q_part     <<<dim3(8, 32), 256, 0, stream>>>(latents, w_lq, part);
  k_reduce     <<<dim3(8, 16), 256, 0, stream>>>(part, b_lq, q, 16);
  k_lnT        <<<32768, 256, 0, stream>>>(x, ln_g, ln_b, h);
  k_wq         <<<2048, 256, 0, stream>>>(w_k, q, wq_t);
  k_scores     <<<dim3(16, 4, 8), 256, 0, stream>>>(h, wq_t, scores, part_ms);
  k_msum       <<<8, 256, 0, stream>>>(part_ms, msum);
  k_pt         <<<dim3(32, 8), 256, 0, stream>>>(scores, msum, h, Tpart);
  k_tred       <<<dim3(128, 2), 256, 0, stream>>>(Tpart, Tbar);
  k_cbar_part  <<<dim3(8, 32), 256, 0, stream>>>(Tbar, w_v, part);
  k_reduce     <<<dim3(8, 8), 256, 0, stream>>>(part, b_v, cbar, 8);
  k_vecmat_part<<<dim3(8, 32), 256, 0, stream>>>(cbar, w_lv, part);
  k_reduce     <<<dim3(8, 8), 256, 0, stream>>>(part, b_lv, pooled, 8);
  k_vecmat_part<<<dim3(8, 32), 256, 0, stream>>>(pooled, w_out, part);
  k_reduce     <<<dim3(8, 8), 256, 0, stream>>>(part, b_out, outv, 8);
  k_resid      <<<2048, 256, 0, stream>>>(x, outv, out);
}